// Round 7
// baseline (300.433 us; speedup 1.0000x reference)
//
#include <hip/hip_runtime.h>
#include <hip/hip_bf16.h>

#define NN 2048
#define BB 8
#define FD 256
#define NEG_SLOPE 0.2f
#define EPSV 1e-7f

typedef __bf16 bf16x8 __attribute__((ext_vector_type(8)));
typedef __bf16 bf16x4 __attribute__((ext_vector_type(4)));
typedef float f32x4 __attribute__((ext_vector_type(4)));

// async 16B global -> LDS (lds base wave-uniform; dest = base + lane*16)
__device__ __forceinline__ void gload16(const __bf16* g, __bf16* l) {
    __builtin_amdgcn_global_load_lds((const __attribute__((address_space(1))) unsigned int*)g,
                                     (__attribute__((address_space(3))) unsigned int*)l,
                                     16, 0, 0);
}

// ---------------- K1S: WT conversion + f32 scores via associativity ----------
// s_src[i] = x[i,:]@(W@a_w[:F]), s_dst likewise. Blocks 0..63: scores (256
// rows each). Blocks 64..319: WT[o][f] = bf16(W[f][o]).
__global__ __launch_bounds__(256) void k1s(const float* __restrict__ W,
                                           const float* __restrict__ a_w,
                                           const float* __restrict__ x,
                                           __bf16* __restrict__ WT,
                                           float* __restrict__ s_src,
                                           float* __restrict__ s_dst) {
    const int bid = blockIdx.x, tid = threadIdx.x;
    if (bid >= 64) {
        int idx = (bid - 64) * 256 + tid;
        int o = idx >> 8, f = idx & 255;
        WT[idx] = (__bf16)W[f * FD + o];
        return;
    }
    __shared__ float aw[2 * FD];
    __shared__ float vs[FD], vd[FD];
    aw[tid] = a_w[tid];
    aw[FD + tid] = a_w[FD + tid];
    __syncthreads();
    {   // v[f] = W[f,:] . a_w halves  (row-contiguous, coalesced)
        const float* wrow = W + (size_t)tid * FD;
        float s1 = 0.f, s2 = 0.f;
#pragma unroll 8
        for (int k = 0; k < FD; k += 4) {
            float4 wv = *(const float4*)(wrow + k);
            s1 += wv.x * aw[k] + wv.y * aw[k + 1] + wv.z * aw[k + 2] + wv.w * aw[k + 3];
            s2 += wv.x * aw[FD + k] + wv.y * aw[FD + k + 1]
                + wv.z * aw[FD + k + 2] + wv.w * aw[FD + k + 3];
        }
        vs[tid] = s1; vd[tid] = s2;
    }
    __syncthreads();
    const int row = bid * 256 + tid;          // 0..16383 = b*NN + i
    const float* xr = x + (size_t)row * FD;
    float ss = 0.f, dd = 0.f;
#pragma unroll 8
    for (int k = 0; k < FD; k += 4) {
        float4 xv = *(const float4*)(xr + k);
        ss += xv.x * vs[k] + xv.y * vs[k + 1] + xv.z * vs[k + 2] + xv.w * vs[k + 3];
        dd += xv.x * vd[k] + xv.y * vd[k + 1] + xv.z * vd[k + 2] + xv.w * vd[k + 3];
    }
    s_src[row] = ss;
    s_dst[row] = dd;
}

// ---------------- K4: den_part[isp][b][j] = partial column sums (proven) ------
__global__ __launch_bounds__(256) void k4_den(const float* __restrict__ A,
                                              const float* __restrict__ s_src,
                                              const float* __restrict__ s_dst,
                                              const float* __restrict__ a_bp,
                                              float* __restrict__ den_part) {
    const int blk = blockIdx.x;
    const int b = blk & 7;
    const int jhalf = (blk >> 3) & 1;
    const int isp = blk >> 4;
    const int i0 = isp * 32;
    const int j = jhalf * 1024 + threadIdx.x * 4;
    __shared__ float ss[32];
    if (threadIdx.x < 32) ss[threadIdx.x] = s_src[b * NN + i0 + threadIdx.x] + a_bp[0];
    __syncthreads();
    float4 sd = *(const float4*)(s_dst + b * NN + j);
    float ax = 0.f, ay = 0.f, az = 0.f, aw = 0.f;
    const float* Ap = A + ((size_t)b * NN + i0) * NN + j;
#pragma unroll 8
    for (int i = 0; i < 32; ++i) {
        float4 a = *(const float4*)(Ap + (size_t)i * NN);
        float si = ss[i];
        float e0 = si + sd.x; e0 = e0 > 0.f ? e0 : NEG_SLOPE * e0;
        float e1 = si + sd.y; e1 = e1 > 0.f ? e1 : NEG_SLOPE * e1;
        float e2 = si + sd.z; e2 = e2 > 0.f ? e2 : NEG_SLOPE * e2;
        float e3 = si + sd.w; e3 = e3 > 0.f ? e3 : NEG_SLOPE * e3;
        ax += a.x * __expf(e0);
        ay += a.y * __expf(e1);
        az += a.z * __expf(e2);
        aw += a.w * __expf(e3);
    }
    float4 r = (float4){ax, ay, az, aw};
    *(float4*)(den_part + (size_t)isp * (BB * NN) + b * NN + j) = r;
}

// ---------------- K2N: Wh GEMM -> normalized transposed bf16 WhT directly -----
// Same MFMA body as the proven k2, but the f32 Wh is never written to global:
// acc -> LDS transpose -> *invd[j] (from den_part, summed in-block) -> bf16
// WhT[b][o][j]. Kills k5 and the 33 MB Wh round-trip.
__global__ __launch_bounds__(256) void k2n(const float* __restrict__ x,
                                           const __bf16* __restrict__ WT,
                                           const float* __restrict__ den_part,
                                           __bf16* __restrict__ WhT) {
    const int wave = threadIdx.x >> 6;
    const int lane = threadIdx.x & 63;
    const int gr0 = blockIdx.x * 32;          // global row base (b*NN + j0)
    const int b = gr0 >> 11;
    const int j0 = gr0 & (NN - 1);
    const int row0 = gr0 + (wave >> 1) * 16;
    const int ohalf = (wave & 1) * 128;
    const int m = lane & 15;
    const int quad = lane >> 4;
    const float* xrow = x + (size_t)(row0 + m) * FD + quad * 8;

    __shared__ float tileT[32][257];
    __shared__ float invd[32];

    if (threadIdx.x < 32) {
        float s = 0.f;
        const float* dp = den_part + b * NN + j0 + threadIdx.x;
#pragma unroll 8
        for (int sI = 0; sI < 64; ++sI) s += dp[(size_t)sI * (BB * NN)];
        invd[threadIdx.x] = 1.f / (s + EPSV);
    }

    f32x4 acc[8];
#pragma unroll
    for (int n = 0; n < 8; ++n) acc[n] = (f32x4){0.f, 0.f, 0.f, 0.f};

    for (int k0 = 0; k0 < FD; k0 += 32) {
        float4 xa = *(const float4*)(xrow + k0);
        float4 xb = *(const float4*)(xrow + k0 + 4);
        bf16x8 af;
        af[0] = (__bf16)xa.x; af[1] = (__bf16)xa.y; af[2] = (__bf16)xa.z; af[3] = (__bf16)xa.w;
        af[4] = (__bf16)xb.x; af[5] = (__bf16)xb.y; af[6] = (__bf16)xb.z; af[7] = (__bf16)xb.w;
#pragma unroll
        for (int n = 0; n < 8; ++n) {
            int o = ohalf + n * 16 + m;
            bf16x8 bf = *(const bf16x8*)(WT + o * FD + k0 + quad * 8);
            acc[n] = __builtin_amdgcn_mfma_f32_16x16x32_bf16(af, bf, acc[n], 0, 0, 0);
        }
    }

    // acc -> LDS transpose: tileT[j_local][o]
    const int jl = (wave >> 1) * 16 + quad * 4;
#pragma unroll
    for (int n = 0; n < 8; ++n) {
        int o = ohalf + n * 16 + m;
#pragma unroll
        for (int r = 0; r < 4; ++r) tileT[jl + r][o] = acc[n][r];
    }
    __syncthreads();

    // writer: thread = o-row; 32 j's, normalized, packed bf16, 64 B store
    const int o = threadIdx.x;
    bf16x8 p0, p1, p2, p3;
#pragma unroll
    for (int jj = 0; jj < 8; ++jj)  p0[jj] = (__bf16)(tileT[jj][o] * invd[jj]);
#pragma unroll
    for (int jj = 0; jj < 8; ++jj)  p1[jj] = (__bf16)(tileT[8 + jj][o] * invd[8 + jj]);
#pragma unroll
    for (int jj = 0; jj < 8; ++jj)  p2[jj] = (__bf16)(tileT[16 + jj][o] * invd[16 + jj]);
#pragma unroll
    for (int jj = 0; jj < 8; ++jj)  p3[jj] = (__bf16)(tileT[24 + jj][o] * invd[24 + jj]);
    __bf16* dst = WhT + (size_t)(b * FD + o) * NN + j0;
    *(bf16x8*)(dst)      = p0;
    *(bf16x8*)(dst + 8)  = p1;
    *(bf16x8*)(dst + 16) = p2;
    *(bf16x8*)(dst + 24) = p3;
}

// ---------------- K6F: fused out = (A*exp(lrelu(e))) @ WhTn^T (proven R6) -----
__global__ __launch_bounds__(256) void k6f(const float* __restrict__ A,
                                           const __bf16* __restrict__ WhT,
                                           const float* __restrict__ s_src,
                                           const float* __restrict__ s_dst,
                                           const float* __restrict__ a_bp,
                                           float* __restrict__ out) {
    __shared__ __bf16 lP[2][64 * 64];     // 8 KiB x 2
    __shared__ __bf16 lB[2][128 * 64];    // 16 KiB x 2  (48 KiB total)
    const int blk = blockIdx.x;
    const int b = blk & 7;
    const int r_ = blk >> 3;
    const int nh = r_ & 1;
    const int mt = r_ >> 1;
    const int i0 = mt * 64;
    const int o0 = nh * 128;
    const int t = threadIdx.x;
    const int w = t >> 6, lane = t & 63;
    const int m = lane & 15, quad = lane >> 4;
    const int wr = w >> 1, wc = w & 1;

    const int srow = lane >> 3;
    const int schunk = (lane & 7) ^ srow;   // pre-swizzled source chunk
    const __bf16* gB = WhT + ((size_t)(b * FD + o0 + w * 8 + srow)) * NN + schunk * 8;

#define STAGEB(buf, step) { \
        const __bf16* gb = gB + (step) * 64; \
        gload16(gb,                   &lB[buf][0] + (w * 8) * 64); \
        gload16(gb + (size_t)32 * NN, &lB[buf][0] + (32 + w * 8) * 64); \
        gload16(gb + (size_t)64 * NN, &lB[buf][0] + (64 + w * 8) * 64); \
        gload16(gb + (size_t)96 * NN, &lB[buf][0] + (96 + w * 8) * 64); \
    }

    const int pr = t >> 2;
    const int pc = (t & 3) * 16;
    const float ssr = s_src[b * NN + i0 + pr] + a_bp[0];
    const float* Ap  = A + ((size_t)(b * NN + i0 + pr)) * NN + pc;
    const float* sdp = s_dst + b * NN + pc;
    const int ch0 = pc >> 3;
    const int sw0 = ((ch0    ) ^ (pr & 7)) * 8;
    const int sw1 = ((ch0 + 1) ^ (pr & 7)) * 8;
    __bf16* lProw = &lP[0][0] + pr * 64;

    float4 a0E, a1E, a2E, a3E, d0E, d1E, d2E, d3E;
    float4 a0O, a1O, a2O, a3O, d0O, d1O, d2O, d3O;
#define LOADP(step, S) { \
        const float* ap = Ap  + (step) * 64; \
        const float* dp = sdp + (step) * 64; \
        a0##S = *(const float4*)(ap + 0);  a1##S = *(const float4*)(ap + 4); \
        a2##S = *(const float4*)(ap + 8);  a3##S = *(const float4*)(ap + 12); \
        d0##S = *(const float4*)(dp + 0);  d1##S = *(const float4*)(dp + 4); \
        d2##S = *(const float4*)(dp + 8);  d3##S = *(const float4*)(dp + 12); \
    }
#define PB1(vv, idx, av, dv) { \
        float e = ssr + dv; e = e > 0.f ? e : NEG_SLOPE * e; \
        vv[idx] = (__bf16)(av * __expf(e)); }
#define PBUILD(buf, S) { \
        bf16x8 v0, v1; \
        PB1(v0, 0, a0##S.x, d0##S.x) PB1(v0, 1, a0##S.y, d0##S.y) \
        PB1(v0, 2, a0##S.z, d0##S.z) PB1(v0, 3, a0##S.w, d0##S.w) \
        PB1(v0, 4, a1##S.x, d1##S.x) PB1(v0, 5, a1##S.y, d1##S.y) \
        PB1(v0, 6, a1##S.z, d1##S.z) PB1(v0, 7, a1##S.w, d1##S.w) \
        PB1(v1, 0, a2##S.x, d2##S.x) PB1(v1, 1, a2##S.y, d2##S.y) \
        PB1(v1, 2, a2##S.z, d2##S.z) PB1(v1, 3, a2##S.w, d2##S.w) \
        PB1(v1, 4, a3##S.x, d3##S.x) PB1(v1, 5, a3##S.y, d3##S.y) \
        PB1(v1, 6, a3##S.z, d3##S.z) PB1(v1, 7, a3##S.w, d3##S.w) \
        *(bf16x8*)(lProw + (buf) * 4096 + sw0) = v0; \
        *(bf16x8*)(lProw + (buf) * 4096 + sw1) = v1; \
    }

#define MFMA_BLOCK(cur) { \
        const __bf16* lPc = &lP[cur][0]; \
        const __bf16* lBc = &lB[cur][0]; \
        _Pragma("unroll") \
        for (int ks = 0; ks < 2; ++ks) { \
            const int kof = (ks * 32 + quad * 8) ^ swz; \
            bf16x8 pa0 = *(const bf16x8*)(lPc + (wr * 32 + m) * 64 + kof); \
            bf16x8 pa1 = *(const bf16x8*)(lPc + (wr * 32 + 16 + m) * 64 + kof); \
            _Pragma("unroll") \
            for (int n = 0; n < 4; ++n) { \
                bf16x8 bfr = *(const bf16x8*)(lBc + (wc * 64 + n * 16 + m) * 64 + kof); \
                acc[0][n] = __builtin_amdgcn_mfma_f32_16x16x32_bf16(pa0, bfr, acc[0][n], 0, 0, 0); \
                acc[1][n] = __builtin_amdgcn_mfma_f32_16x16x32_bf16(pa1, bfr, acc[1][n], 0, 0, 0); \
            } \
        } \
    }

    LOADP(0, E)
    STAGEB(0, 0)
    PBUILD(0, E)
    LOADP(1, O)

    f32x4 acc[2][4];
#pragma unroll
    for (int mi = 0; mi < 2; ++mi)
#pragma unroll
        for (int n = 0; n < 4; ++n) acc[mi][n] = (f32x4){0.f, 0.f, 0.f, 0.f};

    const int swz = (m & 7) * 8;
    for (int kt2 = 0; kt2 < 16; ++kt2) {
        const int kt = kt2 * 2;
        __syncthreads();
        if (kt2 < 15) LOADP(kt + 2, E)
        STAGEB(1, kt + 1)
        MFMA_BLOCK(0)
        PBUILD(1, O)
        __syncthreads();
        if (kt2 < 15) {
            LOADP(kt + 3, O)
            STAGEB(0, kt + 2)
        }
        MFMA_BLOCK(1)
        if (kt2 < 15) PBUILD(0, E)
    }

#pragma unroll
    for (int mi = 0; mi < 2; ++mi)
#pragma unroll
        for (int n = 0; n < 4; ++n) {
            int o = o0 + wc * 64 + n * 16 + m;
#pragma unroll
            for (int rr = 0; rr < 4; ++rr) {
                int orow = i0 + wr * 32 + mi * 16 + quad * 4 + rr;
                out[((size_t)b * NN + orow) * FD + o] = acc[mi][n][rr];
            }
        }
#undef STAGEB
#undef LOADP
#undef PB1
#undef PBUILD
#undef MFMA_BLOCK
}

extern "C" void kernel_launch(void* const* d_in, const int* in_sizes, int n_in,
                              void* d_out, int out_size, void* d_ws, size_t ws_size,
                              hipStream_t stream) {
    const float* A   = (const float*)d_in[0];
    const float* x   = (const float*)d_in[1];
    const float* W   = (const float*)d_in[2];
    const float* a_w = (const float*)d_in[3];
    const float* a_b = (const float*)d_in[4];
    float* out = (float*)d_out;

    char* ws = (char*)d_ws;
    __bf16* WT      = (__bf16*)ws;                      // 131,072 B
    __bf16* WhT     = (__bf16*)(ws + 131072);           // 8,388,608 B
    float*  s_src   = (float*)(ws + 8519680);           // 65,536 B
    float*  s_dst   = (float*)(ws + 8585216);           // 65,536 B
    float*  den_part= (float*)(ws + 8650752);           // 4,194,304 B
                                                        // total = 12,845,056 B

    k1s<<<320, 256, 0, stream>>>(W, a_w, x, WT, s_src, s_dst);
    k4_den<<<1024, 256, 0, stream>>>(A, s_src, s_dst, a_b, den_part);
    k2n<<<512, 256, 0, stream>>>(x, WT, den_part, WhT);
    k6f<<<512, 256, 0, stream>>>(A, WhT, s_src, s_dst, a_b, out);
}